// Round 1
// baseline (179.763 us; speedup 1.0000x reference)
//
#include <hip/hip_runtime.h>
#include <stdint.h>

typedef float f32x16 __attribute__((ext_vector_type(16)));
typedef int v8i __attribute__((ext_vector_type(8)));
typedef int v4i __attribute__((ext_vector_type(4)));

#define BDIM 8192

// fp8 matrices stored 16B-run k-major for the K=64 scaled MFMA:
//   for byte (row, k): S = k>>6 (MFMA step), h = (k>>5)&1 (lane k-half),
//   q = (k>>4)&1 (16B half of the 32B run):
//   addr = S*524288 + h*262144 + q*131072 + row*16 + (k&15)     (1 MB per matrix)
// The 16B granularity keeps global_load_lds staging linear (contiguous
// 2KB per (S,h,q) tile segment) while ds_read_b128 at row*16 stride is
// bank-conflict-free. Reassembling v8i = (q0 16B, q1 16B) reproduces the
// exact 32B k-run byte order, so MFMA fragments are bit-identical to the
// previous direct-from-global version. A and B share the layout; scales
// are uniform 1.0 (E8M0 0x7F).

// fp32 [8192,128] -> fp8 e4m3 (16B-run layout) + fp32 row sum-of-squares.
// grid (512, 2): 16 rows/block. jg = lane&15 handles k = 8jg..8jg+7.
__global__ __launch_bounds__(256) void prep_kernel(const float* __restrict__ out_f,
                                                   const float* __restrict__ tgt_f,
                                                   uint8_t* __restrict__ ak,
                                                   float* __restrict__ xxyy,
                                                   unsigned* __restrict__ cnt) {
    if (blockIdx.x == 0 && blockIdx.y == 0 && threadIdx.x == 0) *cnt = 0u;

    const float* src = blockIdx.y ? tgt_f : out_f;
    uint8_t* dst = ak + (size_t)blockIdx.y * (1u << 20);
    float* nrm = xxyy + (size_t)blockIdx.y * BDIM;

    const int tid = threadIdx.x;
    const int lane = tid & 63;
    const int w = tid >> 6;
    const int jg = lane & 15;
    const int r = blockIdx.x * 16 + w * 4 + (lane >> 4);

    const float4* s4 = (const float4*)(src + (size_t)r * 128 + jg * 8);
    float4 a = s4[0], b = s4[1];

    uint32_t w0 = __builtin_amdgcn_cvt_pk_fp8_f32(a.x, a.y, 0, false);
    w0 = __builtin_amdgcn_cvt_pk_fp8_f32(a.z, a.w, w0, true);
    uint32_t w1 = __builtin_amdgcn_cvt_pk_fp8_f32(b.x, b.y, 0, false);
    w1 = __builtin_amdgcn_cvt_pk_fp8_f32(b.z, b.w, w1, true);

    // k-range 8jg..8jg+7: S = jg>>3, h = (jg>>2)&1, q = (jg>>1)&1,
    // in-run byte offset (jg&1)*8.
    *(uint2*)(dst + (jg >> 3) * 524288 + ((jg >> 2) & 1) * 262144
                  + ((jg >> 1) & 1) * 131072 + r * 16 + (jg & 1) * 8)
        = make_uint2(w0, w1);

    float sq = a.x*a.x + a.y*a.y + a.z*a.z + a.w*a.w
             + b.x*b.x + b.y*b.y + b.z*b.z + b.w*b.w;
    sq += __shfl_xor(sq, 1); sq += __shfl_xor(sq, 2);
    sq += __shfl_xor(sq, 4); sq += __shfl_xor(sq, 8);
    if (jg == 0) nrm[r] = sq;
}

// 128x128 tile per block; C = A * B^T via mfma_scale 32x32x64 f8f6f4 (fp8,
// scales = 1.0). A/B tiles staged once per block into LDS via
// global_load_lds (width 16) -> halves L2 read traffic vs per-wave
// direct-from-global (268 MB -> 134 MB). Final scalar reduce fused in via
// last-block pattern (deterministic fixed-order sum).
__global__ __launch_bounds__(256, 4) void dist_kernel(const uint8_t* __restrict__ Ak,
                                                      const uint8_t* __restrict__ Bk,
                                                      const float* __restrict__ xxg,
                                                      const float* __restrict__ yyg,
                                                      float* __restrict__ partials,
                                                      unsigned* __restrict__ cnt,
                                                      float* __restrict__ outp) {
    __shared__ uint8_t sA[16384] __attribute__((aligned(16)));
    __shared__ uint8_t sB[16384] __attribute__((aligned(16)));
    __shared__ float xxl[128];
    __shared__ float yyl[128];
    __shared__ float wsum[4];
    __shared__ unsigned lastf;

    const int tid = threadIdx.x;
    const int lane = tid & 63;
    const int wid = tid >> 6;
    const int wr = wid >> 1, wc = wid & 1;      // 2x2 wave grid, each wave 64x64
    const int bx = blockIdx.x, by = blockIdx.y;

    // Stage A/B tiles: 32 chunks of 1KB (64 lanes x 16B), 8 per wave.
    // Chunk c: mat = c>>4 (A/B), s = (c&15)>>1 = (S*2+h)*2+q segment,
    // half = c&1 selects rows 0..63 / 64..127 of the 128-row tile segment.
    {
        const int c0 = wid * 8;
        #pragma unroll
        for (int i = 0; i < 8; ++i) {
            int c = c0 + i;
            int mat = c >> 4, rem = c & 15, s = rem >> 1, half = rem & 1;
            int bidx = mat ? by : bx;
            const uint8_t* g = (mat ? Bk : Ak)
                + (s >> 2) * 524288 + ((s >> 1) & 1) * 262144 + (s & 1) * 131072
                + ((size_t)(bidx * 128 + half * 64)) * 16 + lane * 16;
            uint8_t* l = (mat ? sB : sA) + s * 2048 + half * 1024;
            __builtin_amdgcn_global_load_lds(
                (const __attribute__((address_space(1))) unsigned int*)g,
                (__attribute__((address_space(3))) unsigned int*)l, 16, 0, 0);
        }
    }
    if (tid < 128) xxl[tid] = xxg[bx * 128 + tid];
    else           yyl[tid - 128] = yyg[by * 128 + (tid - 128)];
    __syncthreads();

    const int lm = lane & 31;
    const int fh = lane >> 5;                   // k-half within a 64-k step
    const v4i* A4 = (const v4i*)sA;             // [s][row] 16B units
    const v4i* B4 = (const v4i*)sB;

    f32x16 acc[2][2] = {};
    #pragma unroll
    for (int S = 0; S < 2; ++S) {               // two K=64 steps
        const int sb = S * 4 + fh * 2;          // segment base (q=0)
        v4i a0l = A4[(sb + 0) * 128 + wr * 64 + lm];
        v4i a0h = A4[(sb + 1) * 128 + wr * 64 + lm];
        v4i a1l = A4[(sb + 0) * 128 + wr * 64 + 32 + lm];
        v4i a1h = A4[(sb + 1) * 128 + wr * 64 + 32 + lm];
        v4i b0l = B4[(sb + 0) * 128 + wc * 64 + lm];
        v4i b0h = B4[(sb + 1) * 128 + wc * 64 + lm];
        v4i b1l = B4[(sb + 0) * 128 + wc * 64 + 32 + lm];
        v4i b1h = B4[(sb + 1) * 128 + wc * 64 + 32 + lm];
        v8i a0 = __builtin_shufflevector(a0l, a0h, 0, 1, 2, 3, 4, 5, 6, 7);
        v8i a1 = __builtin_shufflevector(a1l, a1h, 0, 1, 2, 3, 4, 5, 6, 7);
        v8i b0 = __builtin_shufflevector(b0l, b0h, 0, 1, 2, 3, 4, 5, 6, 7);
        v8i b1 = __builtin_shufflevector(b1l, b1h, 0, 1, 2, 3, 4, 5, 6, 7);
        acc[0][0] = __builtin_amdgcn_mfma_scale_f32_32x32x64_f8f6f4(
                        a0, b0, acc[0][0], 0, 0, 0, 0x7F7F7F7F, 0, 0x7F7F7F7F);
        acc[0][1] = __builtin_amdgcn_mfma_scale_f32_32x32x64_f8f6f4(
                        a0, b1, acc[0][1], 0, 0, 0, 0x7F7F7F7F, 0, 0x7F7F7F7F);
        acc[1][0] = __builtin_amdgcn_mfma_scale_f32_32x32x64_f8f6f4(
                        a1, b0, acc[1][0], 0, 0, 0, 0x7F7F7F7F, 0, 0x7F7F7F7F);
        acc[1][1] = __builtin_amdgcn_mfma_scale_f32_32x32x64_f8f6f4(
                        a1, b1, acc[1][1], 0, 0, 0, 0x7F7F7F7F, 0, 0x7F7F7F7F);
    }

    // Epilogue: s += sqrt(|xx+yy-2c|)  (d2 ~ [150,400]; abs is a free input
    // modifier on v_sqrt). 2-way split accumulator chains.
    float s0 = 0.0f, s1 = 0.0f;
    #pragma unroll
    for (int tr = 0; tr < 2; ++tr) {
        // xx rows for this tr come in 4 aligned float4 runs:
        // ml = wr*64 + tr*32 + 8*q + 4*fh + e, q=r>>2, e=r&3.
        float xv[16];
        #pragma unroll
        for (int q = 0; q < 4; ++q) {
            float4 t = *(const float4*)&xxl[wr * 64 + tr * 32 + 8 * q + 4 * fh];
            xv[q * 4 + 0] = t.x; xv[q * 4 + 1] = t.y;
            xv[q * 4 + 2] = t.z; xv[q * 4 + 3] = t.w;
        }
        #pragma unroll
        for (int tc = 0; tc < 2; ++tc) {
            float yv = yyl[wc * 64 + tc * 32 + lm];
            #pragma unroll
            for (int r = 0; r < 16; ++r) {
                float d2 = fmaf(-2.0f, acc[tr][tc][r], xv[r] + yv);
                float d = __builtin_amdgcn_sqrtf(__builtin_fabsf(d2));
                if (r & 1) s1 += d; else s0 += d;
            }
        }
    }
    float s = s0 + s1;

    // Diagonal correction: only 64 of 4096 blocks, only waves with wr==wc.
    if (bx == by && wr == wc) {
        #pragma unroll
        for (int t = 0; t < 2; ++t) {
            #pragma unroll
            for (int r = 0; r < 16; ++r) {
                int row = (r & 3) + 8 * (r >> 2) + 4 * fh;
                if (row == lm) {
                    int idx = wr * 64 + t * 32 + row;
                    float d2 = fmaf(-2.0f, acc[t][t][r], xxl[idx] + yyl[idx]);
                    s -= 2.0f * __builtin_amdgcn_sqrtf(__builtin_fabsf(d2));
                }
            }
        }
    }

    #pragma unroll
    for (int off = 32; off > 0; off >>= 1) s += __shfl_down(s, off);
    if (lane == 0) wsum[wid] = s;
    __syncthreads();

    if (tid == 0) {
        float bs = wsum[0] + wsum[1] + wsum[2] + wsum[3];
        __hip_atomic_store(&partials[by * 64 + bx], bs,
                           __ATOMIC_RELEASE, __HIP_MEMORY_SCOPE_AGENT);
        unsigned old = __hip_atomic_fetch_add(cnt, 1u,
                           __ATOMIC_ACQ_REL, __HIP_MEMORY_SCOPE_AGENT);
        lastf = (old == 4095u) ? 1u : 0u;
    }
    __syncthreads();

    // Last finished block performs the deterministic final reduction.
    if (lastf) {
        float s2 = 0.0f;
        #pragma unroll
        for (int i = 0; i < 16; ++i)
            s2 += __hip_atomic_load(&partials[tid + i * 256],
                                    __ATOMIC_RELAXED, __HIP_MEMORY_SCOPE_AGENT);
        #pragma unroll
        for (int off = 32; off > 0; off >>= 1) s2 += __shfl_down(s2, off);
        if (lane == 0) wsum[wid] = s2;
        __syncthreads();
        if (tid == 0)
            outp[0] = (wsum[0] + wsum[1] + wsum[2] + wsum[3]) * (0.1f / 8192.0f);
    }
}

extern "C" void kernel_launch(void* const* d_in, const int* in_sizes, int n_in,
                              void* d_out, int out_size, void* d_ws, size_t ws_size,
                              hipStream_t stream) {
    const float* output = (const float*)d_in[0];
    const float* target = (const float*)d_in[1];

    uint8_t* ws = (uint8_t*)d_ws;
    uint8_t*  ak      = ws;                                      // A fp8 (1MB) + B fp8 (1MB)
    float*    xxyy    = (float*)(ws + (2u << 20));               // xx (32KB) + yy (32KB)
    float*    partial = (float*)(ws + (2u << 20) + (64u << 10)); // 4096 f32
    unsigned* cnt     = (unsigned*)(ws + (2u << 20) + (80u << 10));

    prep_kernel<<<dim3(512, 2), 256, 0, stream>>>(output, target, ak, xxyy, cnt);
    dist_kernel<<<dim3(64, 64), 256, 0, stream>>>(ak, ak + (1u << 20),
                                                  xxyy, xxyy + BDIM, partial,
                                                  cnt, (float*)d_out);
}

// Round 2
// 78.267 us; speedup vs baseline: 2.2968x; 2.2968x over previous
//
#include <hip/hip_runtime.h>
#include <stdint.h>

typedef float f32x16 __attribute__((ext_vector_type(16)));
typedef int v8i __attribute__((ext_vector_type(8)));
typedef int v4i __attribute__((ext_vector_type(4)));

#define BDIM 8192

// fp8 matrices stored 16B-run k-major for the K=64 scaled MFMA:
//   for byte (row, k): S = k>>6 (MFMA step), h = (k>>5)&1 (lane k-half),
//   q = (k>>4)&1 (16B half of the 32B run):
//   addr = S*524288 + h*262144 + q*131072 + row*16 + (k&15)     (1 MB per matrix)
// The 16B granularity keeps global_load_lds staging linear (contiguous
// 2KB per (S,h,q) tile segment) while ds_read_b128 at row*16 stride is
// bank-conflict-free. Reassembling v8i = (q0 16B, q1 16B) reproduces the
// exact 32B k-run byte order. A and B share the layout; scales are
// uniform 1.0 (E8M0 0x7F).

// fp32 [8192,128] -> fp8 e4m3 (16B-run layout) + fp32 row sum-of-squares.
// grid (512, 2): 16 rows/block. jg = lane&15 handles k = 8jg..8jg+7.
__global__ __launch_bounds__(256) void prep_kernel(const float* __restrict__ out_f,
                                                   const float* __restrict__ tgt_f,
                                                   uint8_t* __restrict__ ak,
                                                   float* __restrict__ xxyy) {
    const float* src = blockIdx.y ? tgt_f : out_f;
    uint8_t* dst = ak + (size_t)blockIdx.y * (1u << 20);
    float* nrm = xxyy + (size_t)blockIdx.y * BDIM;

    const int tid = threadIdx.x;
    const int lane = tid & 63;
    const int w = tid >> 6;
    const int jg = lane & 15;
    const int r = blockIdx.x * 16 + w * 4 + (lane >> 4);

    const float4* s4 = (const float4*)(src + (size_t)r * 128 + jg * 8);
    float4 a = s4[0], b = s4[1];

    uint32_t w0 = __builtin_amdgcn_cvt_pk_fp8_f32(a.x, a.y, 0, false);
    w0 = __builtin_amdgcn_cvt_pk_fp8_f32(a.z, a.w, w0, true);
    uint32_t w1 = __builtin_amdgcn_cvt_pk_fp8_f32(b.x, b.y, 0, false);
    w1 = __builtin_amdgcn_cvt_pk_fp8_f32(b.z, b.w, w1, true);

    // k-range 8jg..8jg+7: S = jg>>3, h = (jg>>2)&1, q = (jg>>1)&1,
    // in-run byte offset (jg&1)*8.
    *(uint2*)(dst + (jg >> 3) * 524288 + ((jg >> 2) & 1) * 262144
                  + ((jg >> 1) & 1) * 131072 + r * 16 + (jg & 1) * 8)
        = make_uint2(w0, w1);

    float sq = a.x*a.x + a.y*a.y + a.z*a.z + a.w*a.w
             + b.x*b.x + b.y*b.y + b.z*b.z + b.w*b.w;
    sq += __shfl_xor(sq, 1); sq += __shfl_xor(sq, 2);
    sq += __shfl_xor(sq, 4); sq += __shfl_xor(sq, 8);
    if (jg == 0) nrm[r] = sq;
}

// 128x128 tile per block; C = A * B^T via mfma_scale 32x32x64 f8f6f4 (fp8,
// scales = 1.0). A/B tiles staged once per block into LDS via
// global_load_lds (width 16) -> halves L2 read traffic vs per-wave
// direct-from-global (268 MB -> 134 MB). Plain store of block partial;
// NO agent-scope atomics (round-1's acq_rel tail caused an L2
// writeback/invalidate storm: 125 us, MfmaUtil 2.6%).
__global__ __launch_bounds__(256, 4) void dist_kernel(const uint8_t* __restrict__ Ak,
                                                      const uint8_t* __restrict__ Bk,
                                                      const float* __restrict__ xxg,
                                                      const float* __restrict__ yyg,
                                                      float* __restrict__ partials) {
    __shared__ uint8_t sA[16384] __attribute__((aligned(16)));
    __shared__ uint8_t sB[16384] __attribute__((aligned(16)));
    __shared__ float xxl[128];
    __shared__ float yyl[128];
    __shared__ float wsum[4];

    const int tid = threadIdx.x;
    const int lane = tid & 63;
    const int wid = tid >> 6;
    const int wr = wid >> 1, wc = wid & 1;      // 2x2 wave grid, each wave 64x64
    const int bx = blockIdx.x, by = blockIdx.y;

    // Stage A/B tiles: 32 chunks of 1KB (64 lanes x 16B), 8 per wave.
    // Chunk c: mat = c>>4 (A/B), s = (c&15)>>1 = (S*2+h)*2+q segment,
    // half = c&1 selects rows 0..63 / 64..127 of the 128-row tile segment.
    {
        const int c0 = wid * 8;
        #pragma unroll
        for (int i = 0; i < 8; ++i) {
            int c = c0 + i;
            int mat = c >> 4, rem = c & 15, s = rem >> 1, half = rem & 1;
            int bidx = mat ? by : bx;
            const uint8_t* g = (mat ? Bk : Ak)
                + (s >> 2) * 524288 + ((s >> 1) & 1) * 262144 + (s & 1) * 131072
                + ((size_t)(bidx * 128 + half * 64)) * 16 + lane * 16;
            uint8_t* l = (mat ? sB : sA) + s * 2048 + half * 1024;
            __builtin_amdgcn_global_load_lds(
                (const __attribute__((address_space(1))) unsigned int*)g,
                (__attribute__((address_space(3))) unsigned int*)l, 16, 0, 0);
        }
    }
    if (tid < 128) xxl[tid] = xxg[bx * 128 + tid];
    else           yyl[tid - 128] = yyg[by * 128 + (tid - 128)];
    __syncthreads();

    const int lm = lane & 31;
    const int fh = lane >> 5;                   // k-half within a 64-k step
    const v4i* A4 = (const v4i*)sA;             // [s][row] 16B units
    const v4i* B4 = (const v4i*)sB;

    f32x16 acc[2][2] = {};
    #pragma unroll
    for (int S = 0; S < 2; ++S) {               // two K=64 steps
        const int sb = S * 4 + fh * 2;          // segment base (q=0)
        v4i a0l = A4[(sb + 0) * 128 + wr * 64 + lm];
        v4i a0h = A4[(sb + 1) * 128 + wr * 64 + lm];
        v4i a1l = A4[(sb + 0) * 128 + wr * 64 + 32 + lm];
        v4i a1h = A4[(sb + 1) * 128 + wr * 64 + 32 + lm];
        v4i b0l = B4[(sb + 0) * 128 + wc * 64 + lm];
        v4i b0h = B4[(sb + 1) * 128 + wc * 64 + lm];
        v4i b1l = B4[(sb + 0) * 128 + wc * 64 + 32 + lm];
        v4i b1h = B4[(sb + 1) * 128 + wc * 64 + 32 + lm];
        v8i a0 = __builtin_shufflevector(a0l, a0h, 0, 1, 2, 3, 4, 5, 6, 7);
        v8i a1 = __builtin_shufflevector(a1l, a1h, 0, 1, 2, 3, 4, 5, 6, 7);
        v8i b0 = __builtin_shufflevector(b0l, b0h, 0, 1, 2, 3, 4, 5, 6, 7);
        v8i b1 = __builtin_shufflevector(b1l, b1h, 0, 1, 2, 3, 4, 5, 6, 7);
        acc[0][0] = __builtin_amdgcn_mfma_scale_f32_32x32x64_f8f6f4(
                        a0, b0, acc[0][0], 0, 0, 0, 0x7F7F7F7F, 0, 0x7F7F7F7F);
        acc[0][1] = __builtin_amdgcn_mfma_scale_f32_32x32x64_f8f6f4(
                        a0, b1, acc[0][1], 0, 0, 0, 0x7F7F7F7F, 0, 0x7F7F7F7F);
        acc[1][0] = __builtin_amdgcn_mfma_scale_f32_32x32x64_f8f6f4(
                        a1, b0, acc[1][0], 0, 0, 0, 0x7F7F7F7F, 0, 0x7F7F7F7F);
        acc[1][1] = __builtin_amdgcn_mfma_scale_f32_32x32x64_f8f6f4(
                        a1, b1, acc[1][1], 0, 0, 0, 0x7F7F7F7F, 0, 0x7F7F7F7F);
    }

    // Epilogue: s += sqrt(|xx+yy-2c|)  (d2 ~ [150,400]; abs is a free input
    // modifier on v_sqrt). 2-way split accumulator chains.
    float s0 = 0.0f, s1 = 0.0f;
    #pragma unroll
    for (int tr = 0; tr < 2; ++tr) {
        // xx rows for this tr come in 4 aligned float4 runs:
        // ml = wr*64 + tr*32 + 8*q + 4*fh + e, q=r>>2, e=r&3.
        float xv[16];
        #pragma unroll
        for (int q = 0; q < 4; ++q) {
            float4 t = *(const float4*)&xxl[wr * 64 + tr * 32 + 8 * q + 4 * fh];
            xv[q * 4 + 0] = t.x; xv[q * 4 + 1] = t.y;
            xv[q * 4 + 2] = t.z; xv[q * 4 + 3] = t.w;
        }
        #pragma unroll
        for (int tc = 0; tc < 2; ++tc) {
            float yv = yyl[wc * 64 + tc * 32 + lm];
            #pragma unroll
            for (int r = 0; r < 16; ++r) {
                float d2 = fmaf(-2.0f, acc[tr][tc][r], xv[r] + yv);
                float d = __builtin_amdgcn_sqrtf(__builtin_fabsf(d2));
                if (r & 1) s1 += d; else s0 += d;
            }
        }
    }
    float s = s0 + s1;

    // Diagonal correction: only 64 of 4096 blocks, only waves with wr==wc.
    if (bx == by && wr == wc) {
        #pragma unroll
        for (int t = 0; t < 2; ++t) {
            #pragma unroll
            for (int r = 0; r < 16; ++r) {
                int row = (r & 3) + 8 * (r >> 2) + 4 * fh;
                if (row == lm) {
                    int idx = wr * 64 + t * 32 + row;
                    float d2 = fmaf(-2.0f, acc[t][t][r], xxl[idx] + yyl[idx]);
                    s -= 2.0f * __builtin_amdgcn_sqrtf(__builtin_fabsf(d2));
                }
            }
        }
    }

    #pragma unroll
    for (int off = 32; off > 0; off >>= 1) s += __shfl_down(s, off);
    if (lane == 0) wsum[wid] = s;
    __syncthreads();
    if (tid == 0) partials[by * 64 + bx] = wsum[0] + wsum[1] + wsum[2] + wsum[3];
}

__global__ __launch_bounds__(256) void reduce_kernel(const float* __restrict__ partials,
                                                     float* __restrict__ out) {
    __shared__ float wsum[4];
    float s = 0.0f;
    #pragma unroll
    for (int i = 0; i < 16; ++i) s += partials[threadIdx.x + i * 256];
    #pragma unroll
    for (int off = 32; off > 0; off >>= 1) s += __shfl_down(s, off);
    int lane = threadIdx.x & 63, wid = threadIdx.x >> 6;
    if (lane == 0) wsum[wid] = s;
    __syncthreads();
    if (threadIdx.x == 0)
        out[0] = (wsum[0] + wsum[1] + wsum[2] + wsum[3]) * (0.1f / 8192.0f);
}

extern "C" void kernel_launch(void* const* d_in, const int* in_sizes, int n_in,
                              void* d_out, int out_size, void* d_ws, size_t ws_size,
                              hipStream_t stream) {
    const float* output = (const float*)d_in[0];
    const float* target = (const float*)d_in[1];

    uint8_t* ws = (uint8_t*)d_ws;
    uint8_t* ak      = ws;                                      // A fp8 (1MB) + B fp8 (1MB)
    float*   xxyy    = (float*)(ws + (2u << 20));               // xx (32KB) + yy (32KB)
    float*   partial = (float*)(ws + (2u << 20) + (64u << 10)); // 4096 f32

    prep_kernel<<<dim3(512, 2), 256, 0, stream>>>(output, target, ak, xxyy);
    dist_kernel<<<dim3(64, 64), 256, 0, stream>>>(ak, ak + (1u << 20),
                                                  xxyy, xxyy + BDIM, partial);
    reduce_kernel<<<1, 256, 0, stream>>>(partial, (float*)d_out);
}